// Round 6
// baseline (405.370 us; speedup 1.0000x reference)
//
#include <hip/hip_runtime.h>
#include <hip/hip_bf16.h>
#include <hip/hip_fp8.h>

#define HALF 4096
#define NTOT 8192
#define D 128
#define KS2 3.79828256f   // sqrt(10*log2(e)); acc = s_ij*log2(e), e = exp2(acc)

typedef __attribute__((ext_vector_type(4))) float f32x4;

__device__ __forceinline__ float wave_sum64(float v) {
#pragma unroll
    for (int m = 32; m >= 1; m >>= 1) v += __shfl_xor(v, m);
    return v;
}

// Zeroes the grid-barrier counter. Runs after the harness's workspace poison
// fill (stream order), before the fused kernel — so every launch starts from
// a known state regardless of prior launches (R5 failure: counter in d_out was
// only zeroed on the FIRST launch; reset() re-poisons workspace but not d_out).
__global__ void init_kernel(unsigned int* __restrict__ ctr) { *ctr = 0u; }

// Single fused kernel, regular launch (graph-capture-safe), 1024 x 256 =
// exactly 4 blocks/CU x 256 CU; __launch_bounds__(256,4) caps regs at 128 so
// ALL blocks are co-resident -> hand-rolled grid barrier cannot deadlock.
// Cross-XCD visibility of plain stores: __threadfence() (agent scope) emits
// L2 writeback/invalidate on gfx950 (per-XCD L2s aren't coherent; the fence +
// device-scope atomic is the sanctioned §6-G16 mechanism).
//   phase A: fp8 cast + packed store + pos/self dots   (R3-verified math)
//   barrier: add -> spin >= 1024
//   phase B: gram row-sum sweep                        (R3-verified body)
//   barrier: add -> 2048; blocks >= 32 EXIT (not needed again, no spin)
//   phase C: blocks 0..31 rowterm; partial store; fence; add; the block
//            seeing prev==2079 acquires, sums 32 partials, writes loss.
__global__ __launch_bounds__(256, 4) void fused_kernel(
    const float* __restrict__ f1, const float* __restrict__ f2,
    unsigned char* __restrict__ xs, float* __restrict__ E1p,
    float* __restrict__ spos, float* __restrict__ sii2,
    float* __restrict__ partials, unsigned int* __restrict__ ctr,
    float* __restrict__ out) {
    const int bid = blockIdx.x;
    const int t = threadIdx.x;

    // ---------------- Phase A: cast + pos/self dots -------------------------
    {
        int w = (bid * 256 + t) >> 6;   // pair index b, 0..4095 (one wave per pair)
        int l = t & 63;
        float2 a1 = ((const float2*)(f1 + (size_t)w * D))[l];
        float2 a2 = ((const float2*)(f2 + (size_t)w * D))[l];

        __hip_fp8_e4m3 q1x(a1.x * KS2), q1y(a1.y * KS2);
        __hip_fp8_e4m3 q2x(a2.x * KS2), q2y(a2.y * KS2);

        // thread covers X[w][2l..2l+2): k = l>>4, quad = (l>>2)&3, j = (l&3)*2
        int g = w >> 4, lrow = w & 15;
        int k = l >> 4, quad = (l >> 2) & 3, j = (l & 3) * 2;
        size_t off = (size_t)g * 2048 + k * 512 + (quad * 16 + lrow) * 8 + j;
        *(unsigned short*)(xs + off) =
            (unsigned short)(q1x.__x | ((unsigned short)q1y.__x << 8));
        *(unsigned short*)(xs + off + 256 * 2048) =
            (unsigned short)(q2x.__x | ((unsigned short)q2y.__x << 8));

        // self-sim from the SAME fp8-rounded values (cancels vs MFMA diagonal)
        float b1x = (float)q1x, b1y = (float)q1y;
        float b2x = (float)q2x, b2y = (float)q2y;
        float s1 = b1x * b1x + b1y * b1y;
        float s2 = b2x * b2x + b2y * b2y;
        float d  = a1.x * a2.x + a1.y * a2.y;
        s1 = wave_sum64(s1); s2 = wave_sum64(s2); d = wave_sum64(d);
        if (l == 0) {
            sii2[w] = s1; sii2[w + HALF] = s2;
            float sp = d * 10.0f;
            spos[w] = sp; spos[w + HALF] = sp;
        }
    }
    // ---- barrier 1: all 1024 blocks ----------------------------------------
    __threadfence();            // release: flush xs/spos/sii2 stores
    __syncthreads();
    if (t == 0) {
        atomicAdd(ctr, 1u);
        while (atomicAdd(ctr, 0u) < 1024u) __builtin_amdgcn_s_sleep(1);
    }
    __syncthreads();
    __threadfence();            // acquire: invalidate before remote reads

    // ---------------- Phase B: gram row-sum sweep (R3-verified body) --------
    {
        const int slab = bid & 7;     // 0..7
        const int panel = bid >> 3;   // 0..127
        const int wave = t >> 6, lane = t & 63;
        const int lrow = lane & 15, quad = lane >> 4;

        // A fragments: row group g = panel*4 + r; byte off g*2048 + k*512 + lane*8
        const unsigned char* ab = xs + (size_t)panel * 4 * 2048 + lane * 8;
        long af[4][4];
#pragma unroll
        for (int k = 0; k < 4; ++k)
#pragma unroll
            for (int r = 0; r < 4; ++r)
                af[k][r] = *(const long*)(ab + r * 2048 + k * 512);

        // B base: col group = slab*64 + tt*8 + wave*2 + c (2048 B per group)
        const unsigned char* bb = xs + ((size_t)slab * 64 + wave * 2) * 2048 + lane * 8;
        long bfr[4][2];
#pragma unroll
        for (int k = 0; k < 4; ++k)
#pragma unroll
            for (int c = 0; c < 2; ++c)
                bfr[k][c] = *(const long*)(bb + c * 2048 + k * 512);

        f32x4 rs4[4];
#pragma unroll
        for (int r = 0; r < 4; ++r) rs4[r] = (f32x4){0.f, 0.f, 0.f, 0.f};

#pragma unroll 1
        for (int tt = 0; tt < 8; ++tt) {
            f32x4 a2[4][2];
#pragma unroll
            for (int r = 0; r < 4; ++r)
#pragma unroll
                for (int c = 0; c < 2; ++c) a2[r][c] = (f32x4){0.f, 0.f, 0.f, 0.f};
#pragma unroll
            for (int k = 0; k < 4; ++k)
#pragma unroll
                for (int r = 0; r < 4; ++r)
#pragma unroll
                    for (int c = 0; c < 2; ++c)
                        a2[r][c] = __builtin_amdgcn_mfma_f32_16x16x32_fp8_fp8(af[k][r], bfr[k][c], a2[r][c], 0, 0, 0);

            if (tt < 7) {   // rotate: next tile's loads into the same regs
                const unsigned char* bn = bb + (size_t)(tt + 1) * 8 * 2048;
#pragma unroll
                for (int k = 0; k < 4; ++k)
#pragma unroll
                    for (int c = 0; c < 2; ++c)
                        bfr[k][c] = *(const long*)(bn + c * 2048 + k * 512);
            }

#pragma unroll
            for (int r = 0; r < 4; ++r)
#pragma unroll
                for (int c = 0; c < 2; ++c)
#pragma unroll
                    for (int g = 0; g < 4; ++g)
                        rs4[r][g] += __builtin_amdgcn_exp2f(a2[r][c][g]);
        }

        // reduce over the 16 lanes sharing a quad; disjoint-slot store (no atomics)
        const int slot = slab * 4 + wave;   // 0..31
#pragma unroll
        for (int r = 0; r < 4; ++r) {
#pragma unroll
            for (int g = 0; g < 4; ++g) {
                float v = rs4[r][g];
#pragma unroll
                for (int m = 1; m <= 8; m <<= 1) v += __shfl_xor(v, m);
                if (lrow == 0)
                    E1p[(size_t)slot * NTOT + panel * 64 + r * 16 + quad * 4 + g] = v;
            }
        }
    }
    // ---- barrier 2: add; blocks >= 32 exit, blocks < 32 spin ---------------
    __threadfence();            // release: flush E1p stores
    __syncthreads();
    if (t == 0) atomicAdd(ctr, 1u);
    if (bid >= 32) return;      // not needed for phase C — no spin, just retire
    if (t == 0) {
        while (atomicAdd(ctr, 0u) < 2048u) __builtin_amdgcn_s_sleep(1);
    }
    __syncthreads();
    __threadfence();            // acquire

    // ---------------- Phase C: rowterm (blocks 0..31) -----------------------
    {
        int i = bid * 256 + t;
        float div = 0.f;
#pragma unroll
        for (int s = 0; s < 32; ++s) div += E1p[(size_t)s * NTOT + i];
        div -= __builtin_amdgcn_exp2f(sii2[i]);
        float sp = spos[i];
        float pmt = __expf(sp) / div;
        float term = sp - __logf(div) - 1.0f - __logf(1.0f - pmt);

        term = wave_sum64(term);
        __shared__ float red[4];
        if ((t & 63) == 0) red[t >> 6] = term;
        __syncthreads();
        if (t == 0) {
            partials[bid] = red[0] + red[1] + red[2] + red[3];
            __threadfence();                       // release partial
            unsigned int prev = atomicAdd(ctr, 1u);
            if (prev == 2079u) {                   // last of the 32: finalize
                __threadfence();                   // acquire partials
                float total = 0.f;
#pragma unroll
                for (int s = 0; s < 32; ++s) total += partials[s];
                out[0] = -total * (1.0f / (float)NTOT);
            }
        }
    }
}

extern "C" void kernel_launch(void* const* d_in, const int* in_sizes, int n_in,
                              void* d_out, int out_size, void* d_ws, size_t ws_size,
                              hipStream_t stream) {
    const float* f1 = (const float*)d_in[0];
    const float* f2 = (const float*)d_in[1];
    float* out = (float*)d_out;

    char* ws = (char*)d_ws;
    unsigned char* xs = (unsigned char*)ws;                   // 1 MB packed fp8
    float* E1p  = (float*)(ws + (size_t)NTOT * D);            // 32*8192 f32 = 1 MB
    float* spos = E1p + 32 * NTOT;                            // 8192 f32
    float* sii2 = spos + NTOT;                                // 8192 f32
    float* partials = sii2 + NTOT;                            // 32 f32
    unsigned int* ctr = (unsigned int*)(partials + 32);       // 1 u32, init'd below

    init_kernel<<<1, 1, 0, stream>>>(ctr);
    fused_kernel<<<1024, 256, 0, stream>>>(f1, f2, xs, E1p, spos, sii2, partials, ctr, out);
}

// Round 7
// 399.035 us; speedup vs baseline: 1.0159x; 1.0159x over previous
//
#include <hip/hip_runtime.h>
#include <hip/hip_bf16.h>
#include <hip/hip_fp8.h>

#define HALF 4096
#define NTOT 8192
#define D 128
#define KS2 3.79828256f   // sqrt(10*log2(e)); acc = s_ij*log2(e), e = exp2(acc)

typedef __attribute__((ext_vector_type(4))) float f32x4;

__device__ __forceinline__ float wave_sum64(float v) {
#pragma unroll
    for (int m = 32; m >= 1; m >>= 1) v += __shfl_xor(v, m);
    return v;
}

// Zeroes the grid-barrier counter. Runs after the harness's workspace poison
// fill (stream order), before the fused kernel — known state every launch.
__global__ void init_kernel(unsigned int* __restrict__ ctr) { *ctr = 0u; }

// R6 post-mortem: atomicAdd(ctr,0) POLLING is an RMW — 1024 spinners issuing
// continuous RMWs to one line serialize at the coherence point (~300 ns each,
// ~310 us total, measured). Fix: poll with agent-scope atomic LOAD (no
// ownership, pipelines, doesn't block the adders) + s_sleep(8) backoff.
// Increments remain atomicAdd (1024 total, pipelined at the TCC atomic ALU).
// This is exactly how ROCm's cooperative grid.sync is implemented.
__device__ __forceinline__ unsigned int ctr_poll(const unsigned int* ctr) {
    return __hip_atomic_load(ctr, __ATOMIC_RELAXED, __HIP_MEMORY_SCOPE_AGENT);
}

// Single fused kernel, regular launch (graph-capture-safe), 1024 x 256 =
// exactly 4 blocks/CU x 256 CU; __launch_bounds__(256,4) caps regs at 128 so
// ALL blocks are co-resident -> grid barrier cannot deadlock. Cross-XCD
// visibility of plain stores: __threadfence() (agent scope) around the
// device-scope atomics (§6-G16 mechanism; R6 verified correctness end-to-end).
//   phase A: fp8 cast + packed store + pos/self dots   (R3-verified math)
//   barrier: add -> load-spin >= 1024
//   phase B: gram row-sum sweep                        (R3-verified body)
//   barrier: add -> 2048; blocks >= 32 EXIT (no spin)
//   phase C: blocks 0..31 rowterm; partial store; fence; add; the block
//            seeing prev==2079 acquires, sums 32 partials, writes loss.
__global__ __launch_bounds__(256, 4) void fused_kernel(
    const float* __restrict__ f1, const float* __restrict__ f2,
    unsigned char* __restrict__ xs, float* __restrict__ E1p,
    float* __restrict__ spos, float* __restrict__ sii2,
    float* __restrict__ partials, unsigned int* __restrict__ ctr,
    float* __restrict__ out) {
    const int bid = blockIdx.x;
    const int t = threadIdx.x;

    // ---------------- Phase A: cast + pos/self dots -------------------------
    {
        int w = (bid * 256 + t) >> 6;   // pair index b, 0..4095 (one wave per pair)
        int l = t & 63;
        float2 a1 = ((const float2*)(f1 + (size_t)w * D))[l];
        float2 a2 = ((const float2*)(f2 + (size_t)w * D))[l];

        __hip_fp8_e4m3 q1x(a1.x * KS2), q1y(a1.y * KS2);
        __hip_fp8_e4m3 q2x(a2.x * KS2), q2y(a2.y * KS2);

        // thread covers X[w][2l..2l+2): k = l>>4, quad = (l>>2)&3, j = (l&3)*2
        int g = w >> 4, lrow = w & 15;
        int k = l >> 4, quad = (l >> 2) & 3, j = (l & 3) * 2;
        size_t off = (size_t)g * 2048 + k * 512 + (quad * 16 + lrow) * 8 + j;
        *(unsigned short*)(xs + off) =
            (unsigned short)(q1x.__x | ((unsigned short)q1y.__x << 8));
        *(unsigned short*)(xs + off + 256 * 2048) =
            (unsigned short)(q2x.__x | ((unsigned short)q2y.__x << 8));

        // self-sim from the SAME fp8-rounded values (cancels vs MFMA diagonal)
        float b1x = (float)q1x, b1y = (float)q1y;
        float b2x = (float)q2x, b2y = (float)q2y;
        float s1 = b1x * b1x + b1y * b1y;
        float s2 = b2x * b2x + b2y * b2y;
        float d  = a1.x * a2.x + a1.y * a2.y;
        s1 = wave_sum64(s1); s2 = wave_sum64(s2); d = wave_sum64(d);
        if (l == 0) {
            sii2[w] = s1; sii2[w + HALF] = s2;
            float sp = d * 10.0f;
            spos[w] = sp; spos[w + HALF] = sp;
        }
    }
    // ---- barrier 1: all 1024 blocks (add + LOAD-spin) ----------------------
    __threadfence();            // release: flush xs/spos/sii2 stores
    __syncthreads();
    if (t == 0) {
        atomicAdd(ctr, 1u);
        while (ctr_poll(ctr) < 1024u) __builtin_amdgcn_s_sleep(8);
    }
    __syncthreads();
    __threadfence();            // acquire: invalidate before remote reads

    // ---------------- Phase B: gram row-sum sweep (R3-verified body) --------
    {
        const int slab = bid & 7;     // 0..7
        const int panel = bid >> 3;   // 0..127
        const int wave = t >> 6, lane = t & 63;
        const int lrow = lane & 15, quad = lane >> 4;

        // A fragments: row group g = panel*4 + r; byte off g*2048 + k*512 + lane*8
        const unsigned char* ab = xs + (size_t)panel * 4 * 2048 + lane * 8;
        long af[4][4];
#pragma unroll
        for (int k = 0; k < 4; ++k)
#pragma unroll
            for (int r = 0; r < 4; ++r)
                af[k][r] = *(const long*)(ab + r * 2048 + k * 512);

        // B base: col group = slab*64 + tt*8 + wave*2 + c (2048 B per group)
        const unsigned char* bb = xs + ((size_t)slab * 64 + wave * 2) * 2048 + lane * 8;
        long bfr[4][2];
#pragma unroll
        for (int k = 0; k < 4; ++k)
#pragma unroll
            for (int c = 0; c < 2; ++c)
                bfr[k][c] = *(const long*)(bb + c * 2048 + k * 512);

        f32x4 rs4[4];
#pragma unroll
        for (int r = 0; r < 4; ++r) rs4[r] = (f32x4){0.f, 0.f, 0.f, 0.f};

#pragma unroll 1
        for (int tt = 0; tt < 8; ++tt) {
            f32x4 a2[4][2];
#pragma unroll
            for (int r = 0; r < 4; ++r)
#pragma unroll
                for (int c = 0; c < 2; ++c) a2[r][c] = (f32x4){0.f, 0.f, 0.f, 0.f};
#pragma unroll
            for (int k = 0; k < 4; ++k)
#pragma unroll
                for (int r = 0; r < 4; ++r)
#pragma unroll
                    for (int c = 0; c < 2; ++c)
                        a2[r][c] = __builtin_amdgcn_mfma_f32_16x16x32_fp8_fp8(af[k][r], bfr[k][c], a2[r][c], 0, 0, 0);

            if (tt < 7) {   // rotate: next tile's loads into the same regs
                const unsigned char* bn = bb + (size_t)(tt + 1) * 8 * 2048;
#pragma unroll
                for (int k = 0; k < 4; ++k)
#pragma unroll
                    for (int c = 0; c < 2; ++c)
                        bfr[k][c] = *(const long*)(bn + c * 2048 + k * 512);
            }

#pragma unroll
            for (int r = 0; r < 4; ++r)
#pragma unroll
                for (int c = 0; c < 2; ++c)
#pragma unroll
                    for (int g = 0; g < 4; ++g)
                        rs4[r][g] += __builtin_amdgcn_exp2f(a2[r][c][g]);
        }

        // reduce over the 16 lanes sharing a quad; disjoint-slot store (no atomics)
        const int slot = slab * 4 + wave;   // 0..31
#pragma unroll
        for (int r = 0; r < 4; ++r) {
#pragma unroll
            for (int g = 0; g < 4; ++g) {
                float v = rs4[r][g];
#pragma unroll
                for (int m = 1; m <= 8; m <<= 1) v += __shfl_xor(v, m);
                if (lrow == 0)
                    E1p[(size_t)slot * NTOT + panel * 64 + r * 16 + quad * 4 + g] = v;
            }
        }
    }
    // ---- barrier 2: add; blocks >= 32 exit, blocks < 32 load-spin ----------
    __threadfence();            // release: flush E1p stores
    __syncthreads();
    if (t == 0) atomicAdd(ctr, 1u);
    if (bid >= 32) return;      // not needed for phase C — no spin, just retire
    if (t == 0) {
        while (ctr_poll(ctr) < 2048u) __builtin_amdgcn_s_sleep(8);
    }
    __syncthreads();
    __threadfence();            // acquire

    // ---------------- Phase C: rowterm (blocks 0..31) -----------------------
    {
        int i = bid * 256 + t;
        float div = 0.f;
#pragma unroll
        for (int s = 0; s < 32; ++s) div += E1p[(size_t)s * NTOT + i];
        div -= __builtin_amdgcn_exp2f(sii2[i]);
        float sp = spos[i];
        float pmt = __expf(sp) / div;
        float term = sp - __logf(div) - 1.0f - __logf(1.0f - pmt);

        term = wave_sum64(term);
        __shared__ float red[4];
        if ((t & 63) == 0) red[t >> 6] = term;
        __syncthreads();
        if (t == 0) {
            partials[bid] = red[0] + red[1] + red[2] + red[3];
            __threadfence();                       // release partial
            unsigned int prev = atomicAdd(ctr, 1u);
            if (prev == 2079u) {                   // last of the 32: finalize
                __threadfence();                   // acquire partials
                float total = 0.f;
#pragma unroll
                for (int s = 0; s < 32; ++s) total += partials[s];
                out[0] = -total * (1.0f / (float)NTOT);
            }
        }
    }
}

extern "C" void kernel_launch(void* const* d_in, const int* in_sizes, int n_in,
                              void* d_out, int out_size, void* d_ws, size_t ws_size,
                              hipStream_t stream) {
    const float* f1 = (const float*)d_in[0];
    const float* f2 = (const float*)d_in[1];
    float* out = (float*)d_out;

    char* ws = (char*)d_ws;
    unsigned char* xs = (unsigned char*)ws;                   // 1 MB packed fp8
    float* E1p  = (float*)(ws + (size_t)NTOT * D);            // 32*8192 f32 = 1 MB
    float* spos = E1p + 32 * NTOT;                            // 8192 f32
    float* sii2 = spos + NTOT;                                // 8192 f32
    float* partials = sii2 + NTOT;                            // 32 f32
    unsigned int* ctr = (unsigned int*)(partials + 32);       // 1 u32, init'd below

    init_kernel<<<1, 1, 0, stream>>>(ctr);
    fused_kernel<<<1024, 256, 0, stream>>>(f1, f2, xs, E1p, spos, sii2, partials, ctr, out);
}

// Round 8
// 180.992 us; speedup vs baseline: 2.2397x; 2.2047x over previous
//
#include <hip/hip_runtime.h>
#include <hip/hip_bf16.h>
#include <hip/hip_fp8.h>

#define HALF 4096
#define NTOT 8192
#define D 128
#define KS2 3.79828256f   // sqrt(10*log2(e)); acc = s_ij*log2(e), e = exp2(acc)

typedef __attribute__((ext_vector_type(4))) float f32x4;

__device__ __forceinline__ float wave_sum64(float v) {
#pragma unroll
    for (int m = 32; m >= 1; m >>= 1) v += __shfl_xor(v, m);
    return v;
}

// One wave per pair b. Writes x*KS2 as fp8 e4m3 in MFMA-fragment-packed layout
// (R11-proven). Also: spos (exact fp32 positive dot), sii2 (log2-scaled
// self-sim from the SAME fp8-rounded values), and zero-init of acc / done /
// pdone[128] counters used by the fused gram tail.
__global__ void cast_pos_kernel(const float* __restrict__ f1, const float* __restrict__ f2,
                                unsigned char* __restrict__ xs, float* __restrict__ spos,
                                float* __restrict__ sii2, float* __restrict__ acc,
                                unsigned int* __restrict__ done,
                                unsigned int* __restrict__ pdone) {
    if (blockIdx.x == 0) {
        if (threadIdx.x == 0) { *acc = 0.f; *done = 0u; }
        if (threadIdx.x < 128) pdone[threadIdx.x] = 0u;   // visible to next launch (kernel boundary)
    }

    int w = (blockIdx.x * blockDim.x + threadIdx.x) >> 6;   // pair index b, 0..4095
    int l = threadIdx.x & 63;
    float2 a1 = ((const float2*)(f1 + (size_t)w * D))[l];
    float2 a2 = ((const float2*)(f2 + (size_t)w * D))[l];

    __hip_fp8_e4m3 q1x(a1.x * KS2), q1y(a1.y * KS2);
    __hip_fp8_e4m3 q2x(a2.x * KS2), q2y(a2.y * KS2);

    // this thread covers X[w][2l..2l+2): k = l>>4, quad = (l>>2)&3, j = (l&3)*2
    int g = w >> 4, lrow = w & 15;
    int k = l >> 4, quad = (l >> 2) & 3, j = (l & 3) * 2;
    size_t off = (size_t)g * 2048 + k * 512 + (quad * 16 + lrow) * 8 + j;
    *(unsigned short*)(xs + off) =
        (unsigned short)(q1x.__x | ((unsigned short)q1y.__x << 8));
    *(unsigned short*)(xs + off + 256 * 2048) =
        (unsigned short)(q2x.__x | ((unsigned short)q2y.__x << 8));

    // self-sim from the SAME fp8-rounded values (cancels vs MFMA diagonal)
    float b1x = (float)q1x, b1y = (float)q1y;
    float b2x = (float)q2x, b2y = (float)q2y;
    float s1 = b1x * b1x + b1y * b1y;
    float s2 = b2x * b2x + b2y * b2y;
    float d  = a1.x * a2.x + a1.y * a2.y;
    s1 = wave_sum64(s1); s2 = wave_sum64(s2); d = wave_sum64(d);
    if (l == 0) {
        sii2[w] = s1; sii2[w + HALF] = s2;
        float sp = d * 10.0f;
        spos[w] = sp; spos[w + HALF] = sp;
    }
}

// Gram row-sum sweep (R3-verified body, untouched) + FUSED ROWTERM TAIL.
// R6/R7 lesson: a 1024-way single-counter grid barrier costs ~330 us on this
// part (cross-XCD RMW serialization; poll mechanics irrelevant). So: NO grid
// barrier. Instead, 128 per-panel counters with 8 adds each. After a block's
// disjoint E1p stores: fence -> atomicAdd(pdone[panel]); the block observing
// prev==7 (release/acquire protocol verified correct in R6/R7 phase C) owns
// the panel: its wave 0 computes the closed-form rowterm for the panel's 64
// rows (div summed s=0..31 ascending — bit-identical to the old rowterm),
// adds one partial into acc, and the 128th finisher writes out. Removes the
// third launch + its gap; rowterm work overlaps other panels' gram compute.
__global__ __launch_bounds__(256, 4) void gram_kernel(const unsigned char* __restrict__ xs,
                                                      float* __restrict__ E1p,
                                                      const float* __restrict__ spos,
                                                      const float* __restrict__ sii2,
                                                      float* __restrict__ acc,
                                                      unsigned int* __restrict__ done,
                                                      unsigned int* __restrict__ pdone,
                                                      float* __restrict__ out) {
    const int slab = blockIdx.x;    // 0..7
    const int panel = blockIdx.y;   // 0..127
    const int t = threadIdx.x;
    const int wave = t >> 6, lane = t & 63;
    const int lrow = lane & 15, quad = lane >> 4;

    // A fragments: row group g = panel*4 + r; byte off g*2048 + k*512 + lane*8
    const unsigned char* ab = xs + (size_t)panel * 4 * 2048 + lane * 8;
    long af[4][4];
#pragma unroll
    for (int k = 0; k < 4; ++k)
#pragma unroll
        for (int r = 0; r < 4; ++r)
            af[k][r] = *(const long*)(ab + r * 2048 + k * 512);

    // B base: col group = slab*64 + tt*8 + wave*2 + c (2048 B per group)
    const unsigned char* bb = xs + ((size_t)slab * 64 + wave * 2) * 2048 + lane * 8;
    long bfr[4][2];
#pragma unroll
    for (int k = 0; k < 4; ++k)
#pragma unroll
        for (int c = 0; c < 2; ++c)
            bfr[k][c] = *(const long*)(bb + c * 2048 + k * 512);

    f32x4 rs4[4];
#pragma unroll
    for (int r = 0; r < 4; ++r) rs4[r] = (f32x4){0.f, 0.f, 0.f, 0.f};

#pragma unroll 1
    for (int tt = 0; tt < 8; ++tt) {
        f32x4 a2[4][2];
#pragma unroll
        for (int r = 0; r < 4; ++r)
#pragma unroll
            for (int c = 0; c < 2; ++c) a2[r][c] = (f32x4){0.f, 0.f, 0.f, 0.f};
#pragma unroll
        for (int k = 0; k < 4; ++k)
#pragma unroll
            for (int r = 0; r < 4; ++r)
#pragma unroll
                for (int c = 0; c < 2; ++c)
                    a2[r][c] = __builtin_amdgcn_mfma_f32_16x16x32_fp8_fp8(af[k][r], bfr[k][c], a2[r][c], 0, 0, 0);

        if (tt < 7) {   // rotate: next tile's loads into the same regs
            const unsigned char* bn = bb + (size_t)(tt + 1) * 8 * 2048;
#pragma unroll
            for (int k = 0; k < 4; ++k)
#pragma unroll
                for (int c = 0; c < 2; ++c)
                    bfr[k][c] = *(const long*)(bn + c * 2048 + k * 512);
        }

#pragma unroll
        for (int r = 0; r < 4; ++r)
#pragma unroll
            for (int c = 0; c < 2; ++c)
#pragma unroll
                for (int g = 0; g < 4; ++g)
                    rs4[r][g] += __builtin_amdgcn_exp2f(a2[r][c][g]);
    }

    // reduce over the 16 lanes sharing a quad; disjoint-slot store (no atomics)
    const int slot = slab * 4 + wave;   // 0..31
#pragma unroll
    for (int r = 0; r < 4; ++r) {
#pragma unroll
        for (int g = 0; g < 4; ++g) {
            float v = rs4[r][g];
#pragma unroll
            for (int m = 1; m <= 8; m <<= 1) v += __shfl_xor(v, m);
            if (lrow == 0)
                E1p[(size_t)slot * NTOT + panel * 64 + r * 16 + quad * 4 + g] = v;
        }
    }

    // ---- fused rowterm tail: per-panel done counter (8 adds, low contention)
    __threadfence();                 // release this block's E1p stores
    __syncthreads();                 // all waves' stores fenced before the add
    __shared__ int winner;
    if (t == 0) winner = (atomicAdd(&pdone[panel], 1u) == 7u) ? 1 : 0;
    __syncthreads();
    if (!winner) return;
    __threadfence();                 // acquire: other slabs' E1p stores now visible

    if (t < 64) {                    // wave 0: one row per lane, 64 rows of this panel
        int i = panel * 64 + t;
        float div = 0.f;
#pragma unroll
        for (int s = 0; s < 32; ++s) div += E1p[(size_t)s * NTOT + i];   // s-ascending: bit-identical to old rowterm
        div -= __builtin_amdgcn_exp2f(sii2[i]);
        float sp = spos[i];
        float pmt = __expf(sp) / div;
        float term = sp - __logf(div) - 1.0f - __logf(1.0f - pmt);

        term = wave_sum64(term);
        if (t == 0) {
            atomicAdd(acc, term);
            __threadfence();
            unsigned int prev = atomicAdd(done, 1u);
            if (prev == 127u) {      // last panel: atomic read-back, single write
                float total = atomicAdd(acc, 0.0f);
                out[0] = -total * (1.0f / (float)NTOT);
            }
        }
    }
}

extern "C" void kernel_launch(void* const* d_in, const int* in_sizes, int n_in,
                              void* d_out, int out_size, void* d_ws, size_t ws_size,
                              hipStream_t stream) {
    const float* f1 = (const float*)d_in[0];
    const float* f2 = (const float*)d_in[1];
    float* out = (float*)d_out;

    char* ws = (char*)d_ws;
    unsigned char* xs = (unsigned char*)ws;                   // 1 MB packed fp8
    float* E1p  = (float*)(ws + (size_t)NTOT * D);            // 32*8192 f32 = 1 MB
    float* spos = E1p + 32 * NTOT;                            // 8192 f32
    float* sii2 = spos + NTOT;                                // 8192 f32
    float* acc  = sii2 + NTOT;                                // 1 f32
    unsigned int* done  = (unsigned int*)(acc + 1);           // 1 u32
    unsigned int* pdone = done + 1;                           // 128 u32

    cast_pos_kernel<<<1024, 256, 0, stream>>>(f1, f2, xs, spos, sii2, acc, done, pdone);
    gram_kernel<<<dim3(8, 128), 256, 0, stream>>>(xs, E1p, spos, sii2, acc, done, pdone, out);
}

// Round 9
// 84.126 us; speedup vs baseline: 4.8186x; 2.1514x over previous
//
#include <hip/hip_runtime.h>
#include <hip/hip_bf16.h>
#include <hip/hip_fp8.h>

#define HALF 4096
#define NTOT 8192
#define D 128
#define KS2 3.79828256f   // sqrt(10*log2(e)); acc = s_ij*log2(e), e = exp2(acc)

typedef __attribute__((ext_vector_type(4))) float f32x4;

__device__ __forceinline__ float wave_sum64(float v) {
#pragma unroll
    for (int m = 32; m >= 1; m >>= 1) v += __shfl_xor(v, m);
    return v;
}

// One wave per pair b. Writes x*KS2 as fp8 e4m3 in MFMA-fragment-packed layout:
// byte offset g*2048 + k*512 + (quad*16+lrow)*8 + j <-> X[g*16+lrow][k*32+quad*8+j]
// (R11-proven). Also: spos[b] (exact fp32 positive dot), sii2[row] = log2-scaled
// self-sim from the SAME fp8-rounded values (exact diagonal cancellation), and
// zero-init of the acc/done counters used by rowterm.
__global__ void cast_pos_kernel(const float* __restrict__ f1, const float* __restrict__ f2,
                                unsigned char* __restrict__ xs, float* __restrict__ spos,
                                float* __restrict__ sii2, float* __restrict__ acc,
                                unsigned int* __restrict__ done) {
    if (blockIdx.x == 0 && threadIdx.x == 0) { *acc = 0.f; *done = 0u; }

    int w = (blockIdx.x * blockDim.x + threadIdx.x) >> 6;   // pair index b, 0..4095
    int l = threadIdx.x & 63;
    float2 a1 = ((const float2*)(f1 + (size_t)w * D))[l];
    float2 a2 = ((const float2*)(f2 + (size_t)w * D))[l];

    __hip_fp8_e4m3 q1x(a1.x * KS2), q1y(a1.y * KS2);
    __hip_fp8_e4m3 q2x(a2.x * KS2), q2y(a2.y * KS2);

    // this thread covers X[w][2l..2l+2): k = l>>4, quad = (l>>2)&3, j = (l&3)*2
    int g = w >> 4, lrow = w & 15;
    int k = l >> 4, quad = (l >> 2) & 3, j = (l & 3) * 2;
    size_t off = (size_t)g * 2048 + k * 512 + (quad * 16 + lrow) * 8 + j;
    *(unsigned short*)(xs + off) =
        (unsigned short)(q1x.__x | ((unsigned short)q1y.__x << 8));
    *(unsigned short*)(xs + off + 256 * 2048) =
        (unsigned short)(q2x.__x | ((unsigned short)q2y.__x << 8));

    // self-sim from the SAME fp8-rounded values (cancels vs MFMA diagonal)
    float b1x = (float)q1x, b1y = (float)q1y;
    float b2x = (float)q2x, b2y = (float)q2y;
    float s1 = b1x * b1x + b1y * b1y;
    float s2 = b2x * b2x + b2y * b2y;
    float d  = a1.x * a2.x + a1.y * a2.y;
    s1 = wave_sum64(s1); s2 = wave_sum64(s2); d = wave_sum64(d);
    if (l == 0) {
        sii2[w] = s1; sii2[w + HALF] = s2;
        float sp = d * 10.0f;
        spos[w] = sp; spos[w + HALF] = sp;
    }
}

// Gram row-sum sweep (R1-verified body) + L2-WARM PREFETCH preamble.
// R3/R8 accounting: pass-1 gram = 27 us vs 13.5 warm — the cold premium is
// post-cast operand misses (L1+L2 cold after the kernel-boundary writeback)
// serializing through the 8-step tt pipeline (~320 cyc exp2 cover vs ~900 cyc
// miss). Fix: touch the block's A-panel (8 KB) + B-slice (128 KB, shared by
// the 128 co-XCD blocks) with <=9 independent dword loads per thread BEFORE
// the fragment loads — every cold miss is in flight at once (MSHR-merged with
// af/bfr/tt loads) instead of trickling per-tt. Plain C++ loads (compiler
// tracks waitcnt; no asm register hazard); DCE-proofed via opaque sink and a
// no-op-body branch at kernel end. NO fences/atomics anywhere in this kernel
// (R8: one __threadfence per block = ~135 us fence storm; R11 prior session).
__global__ __launch_bounds__(256, 4) void gram_kernel(const unsigned char* __restrict__ xs,
                                                      float* __restrict__ E1p) {
    const int slab = blockIdx.x;    // 0..7
    const int panel = blockIdx.y;   // 0..127
    const int t = threadIdx.x;
    const int wave = t >> 6, lane = t & 63;
    const int lrow = lane & 15, quad = lane >> 4;

    // ---- L2-warm prefetch: issue all cold misses up front (max MLP) --------
    unsigned int sink = 0u;
    {
        const unsigned char* pb = xs + (size_t)slab * 64 * 2048;   // B slice, 128 KB
#pragma unroll
        for (int i = 0; i < 8; ++i)
            sink ^= *(const unsigned int*)(pb + i * 16384 + t * 64);
        if (t < 128) {                                             // wave-uniform (waves 0,1)
            const unsigned char* pa = xs + (size_t)panel * 4 * 2048;   // A panel, 8 KB
            sink ^= *(const unsigned int*)(pa + t * 64);
        }
    }

    // A fragments: row group g = panel*4 + r; byte off g*2048 + k*512 + lane*8
    const unsigned char* ab = xs + (size_t)panel * 4 * 2048 + lane * 8;
    long af[4][4];
#pragma unroll
    for (int k = 0; k < 4; ++k)
#pragma unroll
        for (int r = 0; r < 4; ++r)
            af[k][r] = *(const long*)(ab + r * 2048 + k * 512);

    // B base: col group = slab*64 + tt*8 + wave*2 + c (2048 B per group)
    const unsigned char* bb = xs + ((size_t)slab * 64 + wave * 2) * 2048 + lane * 8;
    long bfr[4][2];
#pragma unroll
    for (int k = 0; k < 4; ++k)
#pragma unroll
        for (int c = 0; c < 2; ++c)
            bfr[k][c] = *(const long*)(bb + c * 2048 + k * 512);

    f32x4 rs4[4];
#pragma unroll
    for (int r = 0; r < 4; ++r) rs4[r] = (f32x4){0.f, 0.f, 0.f, 0.f};

#pragma unroll 1
    for (int tt = 0; tt < 8; ++tt) {
        f32x4 a2[4][2];
#pragma unroll
        for (int r = 0; r < 4; ++r)
#pragma unroll
            for (int c = 0; c < 2; ++c) a2[r][c] = (f32x4){0.f, 0.f, 0.f, 0.f};
#pragma unroll
        for (int k = 0; k < 4; ++k)
#pragma unroll
            for (int r = 0; r < 4; ++r)
#pragma unroll
                for (int c = 0; c < 2; ++c)
                    a2[r][c] = __builtin_amdgcn_mfma_f32_16x16x32_fp8_fp8(af[k][r], bfr[k][c], a2[r][c], 0, 0, 0);

        if (tt < 7) {   // rotate: next tile's loads into the same regs
            const unsigned char* bn = bb + (size_t)(tt + 1) * 8 * 2048;
#pragma unroll
            for (int k = 0; k < 4; ++k)
#pragma unroll
                for (int c = 0; c < 2; ++c)
                    bfr[k][c] = *(const long*)(bn + c * 2048 + k * 512);
        }

#pragma unroll
        for (int r = 0; r < 4; ++r)
#pragma unroll
            for (int c = 0; c < 2; ++c)
#pragma unroll
                for (int g = 0; g < 4; ++g)
                    rs4[r][g] += __builtin_amdgcn_exp2f(a2[r][c][g]);
    }

    // reduce over the 16 lanes sharing a quad; disjoint-slot store (no atomics)
    const int slot = slab * 4 + wave;   // 0..31
#pragma unroll
    for (int r = 0; r < 4; ++r) {
#pragma unroll
        for (int g = 0; g < 4; ++g) {
            float v = rs4[r][g];
#pragma unroll
            for (int m = 1; m <= 8; m <<= 1) v += __shfl_xor(v, m);
            if (lrow == 0)
                E1p[(size_t)slot * NTOT + panel * 64 + r * 16 + quad * 4 + g] = v;
        }
    }

    // consume the prefetch sink (no-op body; prevents DCE, no memory effect)
    if (sink == 1u) __builtin_amdgcn_s_sleep(0);
}

// 32 blocks x 256: per-row closed form. div = sum(32 slots) - exp2(sii2).
// sum_j log1p(-P_ij) ~= -1  (sum_j P_ij == 1 exactly; S2/2 ~ 1e-4 dropped).
// Device-scope done-counter: last-finishing block writes the output
// (R9/R10-proven; only 32 blocks -> fence cost negligible).
__global__ void rowterm_kernel(const float* __restrict__ E1p, const float* __restrict__ spos,
                               const float* __restrict__ sii2, float* __restrict__ acc,
                               unsigned int* __restrict__ done, float* __restrict__ out) {
    int i = blockIdx.x * 256 + threadIdx.x;
    float div = 0.f;
#pragma unroll
    for (int s = 0; s < 32; ++s) div += E1p[(size_t)s * NTOT + i];
    div -= __builtin_amdgcn_exp2f(sii2[i]);
    float sp = spos[i];
    float pmt = __expf(sp) / div;
    float term = sp - __logf(div) - 1.0f - __logf(1.0f - pmt);

    term = wave_sum64(term);
    __shared__ float red[4];
    if ((threadIdx.x & 63) == 0) red[threadIdx.x >> 6] = term;
    __syncthreads();
    if (threadIdx.x == 0) {
        atomicAdd(acc, red[0] + red[1] + red[2] + red[3]);
        __threadfence();
        unsigned int prev = atomicAdd(done, 1u);
        if (prev == 31u) {   // last block: atomic read-back, single write
            float total = atomicAdd(acc, 0.0f);
            out[0] = -total * (1.0f / (float)NTOT);
        }
    }
}

extern "C" void kernel_launch(void* const* d_in, const int* in_sizes, int n_in,
                              void* d_out, int out_size, void* d_ws, size_t ws_size,
                              hipStream_t stream) {
    const float* f1 = (const float*)d_in[0];
    const float* f2 = (const float*)d_in[1];
    float* out = (float*)d_out;

    char* ws = (char*)d_ws;
    unsigned char* xs = (unsigned char*)ws;                   // 1 MB packed fp8
    float* E1p  = (float*)(ws + (size_t)NTOT * D);            // 32*8192 f32 = 1 MB
    float* spos = E1p + 32 * NTOT;                            // 8192 f32
    float* sii2 = spos + NTOT;                                // 8192 f32
    float* acc  = sii2 + NTOT;                                // 1 f32
    unsigned int* done = (unsigned int*)(acc + 1);            // 1 u32

    cast_pos_kernel<<<1024, 256, 0, stream>>>(f1, f2, xs, spos, sii2, acc, done);
    gram_kernel<<<dim3(8, 128), 256, 0, stream>>>(xs, E1p);
    rowterm_kernel<<<32, 256, 0, stream>>>(E1p, spos, sii2, acc, done, out);
}